// Round 16
// baseline (230.567 us; speedup 1.0000x reference)
//
#include <hip/hip_runtime.h>
#include <cmath>

#define NPROP 384
#define NB 2
#define NCLS 11
#define NFG 10
#define BC_TOTAL (NB*NFG)          // 20
#define FLAT_PER_IMG (NFG*NPROP)   // 3840
#define DET 100
#define PAIR_LDS_CAP 4096
#define NSLICE 8
#define SLICE_CAP 9600             // worst-case suppress pairs per slice

// ws layout (in 4-byte words)
#define OFF_BOXES 0                // [BC][N][5]  38400
#define OFF_SCORE 38400            // [BC][N]     7680
#define OFF_SCNT  46080            // [BC][8] u32 suppress-pair counts
#define OFF_SPAIR 46240            // [BC][8][SLICE_CAP] u32 suppress pairs (1,536,000)
#define OFF_SUPM  1582240          // [BC][N][12] u32 sup matrices (92,160) — 8B aligned
typedef unsigned long long ull;

__device__ __forceinline__ void mk_corners(float px, float py, float pw, float ph, float pa,
                                           float cxo[4], float cyo[4]) {
    float t = pa * 0.017453292519943295f;
    float ct = cosf(t), st = sinf(t);
    float hx = pw*0.5f, hy = ph*0.5f;
    float lx[4] = {-hx, hx, hx, -hx};
    float ly[4] = {-hy, -hy, hy, hy};
#pragma unroll
    for (int k = 0; k < 4; ++k) {
        cxo[k] = px + lx[k]*ct - ly[k]*st;
        cyo[k] = py + lx[k]*st + ly[k]*ct;
    }
}

// Register-only quirk-faithful intersection area (park-at-centroid + sort-all-24
// + shoelace). Bitonic-32 network keeps everything in VGPRs.
__device__ float inter_area_net(const float ax[4], const float ay[4],
                                const float bx[4], const float by[4]) {
    float d1x[4], d1y[4], d2x[4], d2y[4];
#pragma unroll
    for (int k = 0; k < 4; ++k) {
        int k1 = (k + 1) & 3;
        d1x[k] = ax[k1] - ax[k]; d1y[k] = ay[k1] - ay[k];
        d2x[k] = bx[k1] - bx[k]; d2y[k] = by[k1] - by[k];
    }
    float ex[32], ey[32];
    bool msk[24];
#pragma unroll
    for (int i = 0; i < 4; ++i) {
#pragma unroll
        for (int j = 0; j < 4; ++j) {
            float den = d1x[i]*d2y[j] - d1y[i]*d2x[j];
            float dfx = bx[j]-ax[i], dfy = by[j]-ay[i];
            float dens = (fabsf(den) < 1e-8f) ? 1.0f : den;
            float t = (dfx*d2y[j] - dfy*d2x[j]) / dens;
            float u = (dfx*d1y[i] - dfy*d1x[i]) / dens;
            bool ok = (fabsf(den) >= 1e-8f) && t >= 0.0f && t <= 1.0f
                                            && u >= 0.0f && u <= 1.0f;
            ex[i*4+j] = ax[i] + t*d1x[i];
            ey[i*4+j] = ay[i] + t*d1y[i];
            msk[i*4+j] = ok;
        }
    }
#pragma unroll
    for (int i = 0; i < 4; ++i) {   // corners of A inside B
        bool allp = true, alln = true;
#pragma unroll
        for (int j = 0; j < 4; ++j) {
            float cr = d2x[j]*(ay[i]-by[j]) - d2y[j]*(ax[i]-bx[j]);
            allp = allp && (cr >= -1e-6f);
            alln = alln && (cr <= 1e-6f);
        }
        ex[16+i] = ax[i]; ey[16+i] = ay[i]; msk[16+i] = allp || alln;
    }
#pragma unroll
    for (int i = 0; i < 4; ++i) {   // corners of B inside A
        bool allp = true, alln = true;
#pragma unroll
        for (int j = 0; j < 4; ++j) {
            float cr = d1x[j]*(by[i]-ay[j]) - d1y[j]*(bx[i]-ax[j]);
            allp = allp && (cr >= -1e-6f);
            alln = alln && (cr <= 1e-6f);
        }
        ex[20+i] = bx[i]; ey[20+i] = by[i]; msk[20+i] = allp || alln;
    }
    int nv = 0; float sx = 0.f, sy = 0.f;
#pragma unroll
    for (int k = 0; k < 24; ++k)
        if (msk[k]) { nv++; sx += ex[k]; sy += ey[k]; }
    float fm = (float)(nv > 1 ? nv : 1);
    float cx = sx / fm, cy = sy / fm;
    unsigned key[32];
#pragma unroll
    for (int k = 0; k < 24; ++k) {
        float qx = msk[k] ? ex[k] : cx;
        float qy = msk[k] ? ey[k] : cy;
        ex[k] = qx; ey[k] = qy;
        float dx = qx - cx, dy = qy - cy;        // parked: dx=dy=+0
        float den = fabsf(dx) + fabsf(dy);
        float r = (den > 0.0f) ? dy / den : 0.0f;
        float p = (dx >= 0.0f) ? r : ((dy >= 0.0f) ? 2.0f - r : -2.0f - r);
        p = p + 0.0f;                             // canonicalize -0 -> +0
        unsigned u = __float_as_uint(p);
        u = (u & 0x80000000u) ? ~u : (u | 0x80000000u);
        key[k] = (u & 0xFFFFFFE0u) | (unsigned)k;
    }
#pragma unroll
    for (int k = 24; k < 32; ++k) { key[k] = 0xFFFFFFFFu; ex[k] = 0.f; ey[k] = 0.f; }
#pragma unroll
    for (int k = 2; k <= 32; k <<= 1) {
#pragma unroll
        for (int j = k >> 1; j > 0; j >>= 1) {
#pragma unroll
            for (int i = 0; i < 32; ++i) {
                int l = i ^ j;
                if (l > i) {
                    bool up = ((i & k) == 0);
                    unsigned ka = key[i], kb = key[l];
                    bool sw = up ? (ka > kb) : (ka < kb);
                    float xa = ex[i], xb = ex[l];
                    float ya = ey[i], yb = ey[l];
                    key[i] = sw ? kb : ka; key[l] = sw ? ka : kb;
                    ex[i]  = sw ? xb : xa; ex[l]  = sw ? xa : xb;
                    ey[i]  = sw ? yb : ya; ey[l]  = sw ? ya : yb;
                }
            }
        }
    }
    float s = 0.f;
#pragma unroll
    for (int k = 0; k < 24; ++k) {
        int n = (k + 1 == 24) ? 0 : (k + 1);
        s += ex[k]*ey[n] - ey[k]*ex[n];
    }
    float area = 0.5f * fabsf(s);
    return (nv >= 3) ? area : 0.0f;
}

// K1: 160 blocks (20 bc x 8 slices) x 768 threads — verbatim R14 structure.
__global__ __launch_bounds__(768)
void pairheavy_kernel(const float* __restrict__ logits,
                      const float* __restrict__ boxreg,
                      const float* __restrict__ rrects,
                      float* __restrict__ ws,
                      float* __restrict__ out) {
    __shared__ float pxL[NPROP], pyL[NPROP], pwL[NPROP], phL[NPROP], paL[NPROP];
    __shared__ float areaL[NPROP], scoreL[NPROP];
    __shared__ float axhL[NPROP], ayhL[NPROP];
    __shared__ int   origL[NPROP];
    __shared__ unsigned pairL[PAIR_LDS_CAP];   // 16 KB
    __shared__ int   wbase[16];
    __shared__ int   totS, pcntS, scntS;

    int blk = blockIdx.x, t = threadIdx.x;
    int bc = blk >> 3, slice = blk & 7;
    int b = bc / NFG, cls = (bc % NFG) + 1;
    int wv = t >> 6, lane = t & 63;

    if (slice == 0) {                      // zero d_out once per bc-group
        int g = bc*768 + t;
        if (g < NB*DET*6 + NB*DET) out[g] = 0.0f;
    }
    if (t == 0) { pcntS = 0; scntS = 0; }

    // ---- decode (threads 0..383; global writes gated to slice 0) ----
    float prob = 0.0f;
    if (t < NPROP) {
        int m = b*NPROP + t;
        float lg[NCLS];
        float mx = -INFINITY;
#pragma unroll
        for (int c = 0; c < NCLS; ++c) { lg[c] = logits[m*NCLS+c]; mx = fmaxf(mx, lg[c]); }
        float sum = 0.f;
#pragma unroll
        for (int c = 0; c < NCLS; ++c) sum += expf(lg[c]-mx);
        prob = expf(lg[cls]-mx) / sum;
        float axc = rrects[m*5+0], ayc = rrects[m*5+1];
        float aw  = rrects[m*5+2], ah  = rrects[m*5+3], aa = rrects[m*5+4];
        const float* rel = boxreg + m*(NCLS*5) + cls*5;
        float dx = rel[0] / 10.0f;
        float dy = rel[1] / 10.0f;
        float dw = fminf(rel[2] / 5.0f, 4.1351665567423205f);
        float dh = fminf(rel[3] / 5.0f, 4.1351665567423205f);
        float da = rel[4];
        float px = dx*aw + axc;
        float py = dy*ah + ayc;
        float pw = expf(dw)*aw;
        float ph = expf(dh)*ah;
        float pa = da*57.29577951308232f + aa;
        float xm = pa + 180.0f;
        float r = fmodf(xm, 360.0f);
        if (r < 0.0f) r += 360.0f;
        pa = r - 180.0f;
        pxL[t]=px; pyL[t]=py; pwL[t]=pw; phL[t]=ph; paL[t]=pa;
        areaL[t]=pw*ph; scoreL[t]=prob;
        float th = pa * 0.017453292519943295f;
        float ct = fabsf(cosf(th)), st = fabsf(sinf(th));
        axhL[t] = 0.5f*(pw*ct + ph*st);
        ayhL[t] = 0.5f*(pw*st + ph*ct);
        if (slice == 0) {
            float* boxes = ws + OFF_BOXES;
            int o = bc*NPROP + t;
            boxes[o*5+0]=px; boxes[o*5+1]=py; boxes[o*5+2]=pw; boxes[o*5+3]=ph; boxes[o*5+4]=pa;
            ws[OFF_SCORE + o] = prob;
        }
    }
    // ---- ballot-prefix valid compaction ----
    bool vi = (t < NPROP) && (prob > 0.05f);
    ull vb = __ballot(vi);
    if (lane == 0) wbase[wv] = __popcll(vb);
    __syncthreads();
    if (t == 0) {
        int s = 0;
#pragma unroll
        for (int w = 0; w < 6; ++w) { int c = wbase[w]; wbase[w] = s; s += c; }
        totS = s;
    }
    __syncthreads();
    if (vi) origL[wbase[wv] + (int)__popcll(vb & ((1ull << lane) - 1ull))] = t;
    __syncthreads();
    int cnt = totS;

    unsigned int* spair = (unsigned int*)(ws + OFF_SPAIR) + (bc*NSLICE + slice)*SLICE_CAP;

    // ---- pair enumeration: a = slice + 8*wv + 96*j; AABB-upper-bound cull ----
    for (int a = slice + 8*wv; a < cnt; a += 96) {
        int ia = origL[a];
        float cxa = pxL[ia], cya = pyL[ia], Aa = areaL[ia], sa = scoreL[ia];
        float axa = axhL[ia], aya = ayhL[ia];
        for (int b0 = a + 1; b0 < cnt; b0 += 64) {
            int bb = b0 + lane;
            bool go = false; int ib = 0;
            if (bb < cnt) {
                ib = origL[bb];
                float ox = (axa + axhL[ib]) - fabsf(cxa - pxL[ib]);
                float oy = (aya + ayhL[ib]) - fabsf(cya - pyL[ib]);
                go = (ox > 0.0f) && (oy > 0.0f);
                if (go) {
                    float Ab = areaL[ib];
                    float ub = fminf(ox*oy, fminf(Aa, Ab));
                    go = (3.0f*ub > Aa + Ab);        // else iou <= 0.5 provably
                }
            }
            ull m = __ballot(go);
            int base = 0;
            if (lane == 0 && m) base = atomicAdd(&pcntS, __popcll(m));
            base = __shfl(base, 0);
            if (go) {
                float sb = scoreL[ib];
                bool afirst = (sa > sb) || (sa == sb && ia < ib);
                int hi = afirst ? ia : ib;
                int lo = afirst ? ib : ia;
                int pos = base + (int)__popcll(m & ((1ull << lane) - 1ull));
                if (pos < PAIR_LDS_CAP) {
                    pairL[pos] = ((unsigned)hi << 16) | (unsigned)lo;
                } else {                             // overflow: eval inline
                    float axp[4], ayp[4], bxp[4], byp[4];
                    mk_corners(pxL[hi], pyL[hi], pwL[hi], phL[hi], paL[hi], axp, ayp);
                    mk_corners(pxL[lo], pyL[lo], pwL[lo], phL[lo], paL[lo], bxp, byp);
                    float inter = inter_area_net(axp, ayp, bxp, byp);
                    float iou = inter / (areaL[hi] + areaL[lo] - inter + 1e-8f);
                    if (iou > 0.5f) {
                        int sp = atomicAdd(&scntS, 1);
                        if (sp < SLICE_CAP) spair[sp] = ((unsigned)hi << 10) | (unsigned)lo;
                    }
                }
            }
        }
    }
    __syncthreads();

    // ---- heavy eval over LDS pair list; survivors -> global suppress slice ----
    {
        int np = pcntS; if (np > PAIR_LDS_CAP) np = PAIR_LDS_CAP;
        for (int p = t; p < np; p += 768) {
            unsigned pk = pairL[p];
            int hi = (int)(pk >> 16), lo = (int)(pk & 0xFFFFu);
            float axp[4], ayp[4], bxp[4], byp[4];
            mk_corners(pxL[hi], pyL[hi], pwL[hi], phL[hi], paL[hi], axp, ayp);
            mk_corners(pxL[lo], pyL[lo], pwL[lo], phL[lo], paL[lo], bxp, byp);
            float inter = inter_area_net(axp, ayp, bxp, byp);
            float iou = inter / (areaL[hi] + areaL[lo] - inter + 1e-8f);
            if (iou > 0.5f) {
                int sp = atomicAdd(&scntS, 1);
                if (sp < SLICE_CAP) spair[sp] = ((unsigned)hi << 10) | (unsigned)lo;
            }
        }
    }
    __syncthreads();
    if (t == 0) {
        int n = scntS; if (n > SLICE_CAP) n = SLICE_CAP;
        ((unsigned int*)(ws + OFF_SCNT))[bc*NSLICE + slice] = (unsigned)n;
    }
}

// K2: ONE block per image, 1024 threads. Zero+scatter sup matrices (global,
// block-private region) -> keys (flat-in-image index in low word!) + per-bc
// rank-sort (LDS) -> 10 concurrent register-walk NMS (one wave per bc) ->
// in-LDS kept compaction -> top-100 rank count -> write output.
__global__ __launch_bounds__(1024)
void finish_kernel(float* __restrict__ ws, float* __restrict__ out) {
    __shared__ ull keysL[NFG*NPROP];           // 30720 B (reused as compacted keys)
    __shared__ int orderL[NFG*NPROP];          // 15360 B
    __shared__ unsigned char keepS[NFG*NPROP]; // 3840 B
    __shared__ int nvL[NFG];
    __shared__ int kcntS;
    int b = blockIdx.x, t = threadIdx.x;
    int wv = t >> 6, lane = t & 63;
    ull* supG = (ull*)(ws + OFF_SUPM) + (size_t)b*NFG*NPROP*6;

    for (int k = t; k < NFG*NPROP*6; k += 1024) supG[k] = 0ull;
    if (t < NFG) nvL[t] = 0;
    if (t == 0) kcntS = 0;
    __syncthreads();

    // scatter suppress pairs into this image's sup matrices
    const unsigned int* scnt = (const unsigned int*)(ws + OFF_SCNT);
#pragma unroll
    for (int fg = 0; fg < NFG; ++fg) {
        int bc = b*NFG + fg;
#pragma unroll
        for (int s = 0; s < NSLICE; ++s) {
            int n = (int)scnt[bc*NSLICE + s];
            const unsigned int* sp = (const unsigned int*)(ws + OFF_SPAIR)
                                     + (bc*NSLICE + s)*SLICE_CAP;
            for (int k = t; k < n; k += 1024) {
                unsigned pk = sp[k];
                int hi = (int)(pk >> 10), lo = (int)(pk & 0x3FFu);
                atomicOr((unsigned int*)(supG + (fg*NPROP + hi)*6) + (lo >> 5),
                         1u << (lo & 31));
            }
        }
    }
    // keys for all 10 bcs — low word carries the FLAT-IN-IMAGE index e
    // (= fg*NPROP + tt). Within a bc, ~e orders identically to ~tt (monotone),
    // so per-bc rank-sort/walk semantics are unchanged; across bcs the final
    // top-k tie-break becomes (score desc, flat idx asc) == lax.top_k.
    for (int e = t; e < NFG*NPROP; e += 1024) {
        int fg = e / NPROP, tt = e % NPROP;
        float sc = ws[OFF_SCORE + (b*NFG + fg)*NPROP + tt];
        bool vi = sc > 0.05f;
        keysL[e] = vi ? (((ull)__float_as_uint(sc) << 32) | (ull)(0xFFFFFFFFu - (unsigned)e))
                      : (ull)(0xFFFFFFFFu - (unsigned)e);
        keepS[e] = 0;
        if (vi) atomicAdd(&nvL[fg], 1);
    }
    __syncthreads();
    // rank-sort per bc
    for (int e = t; e < NFG*NPROP; e += 1024) {
        int fg = e / NPROP;
        ull myk = keysL[e];
        const ull* kb = &keysL[fg*NPROP];
        int r = 0;
        for (int k = 0; k < NPROP; k += 8) {
            int acc = 0;
#pragma unroll
            for (int q = 0; q < 8; ++q) acc += (kb[k+q] > myk) ? 1 : 0;
            r += acc;
        }
        orderL[fg*NPROP + r] = e % NPROP;
    }
    __syncthreads();
    // 10 concurrent register walks (wave wv handles bc fg=wv)
    if (wv < NFG) {
        int fg = wv;
        int NV = nvL[fg];
        const int* ob = &orderL[fg*NPROP];
        int ord0 = ob[lane],      ord1 = ob[64+lane];
        int ord2 = ob[128+lane],  ord3 = ob[192+lane];
        int ord4 = ob[256+lane],  ord5 = ob[320+lane];
        const ull* sg = supG + fg*NPROP*6;
        ull mask = 0ull;
        int o_cur = __shfl(ord0, 0);
        ull row_cur = (lane < 6) ? sg[o_cur*6 + lane] : 0ull;
        for (int p = 0; p < NV; ++p) {
            int pn = (p + 1 < NPROP) ? (p + 1) : 0;
            int seg = pn >> 6, sl = pn & 63;
            int on = __shfl(ord0, sl);
            on = (seg == 1) ? __shfl(ord1, sl) : on;
            on = (seg == 2) ? __shfl(ord2, sl) : on;
            on = (seg == 3) ? __shfl(ord3, sl) : on;
            on = (seg == 4) ? __shfl(ord4, sl) : on;
            on = (seg == 5) ? __shfl(ord5, sl) : on;
            ull row_next = (lane < 6) ? sg[on*6 + lane] : 0ull;  // prefetch
            bool myhit = (lane == (o_cur >> 6)) && ((mask >> (o_cur & 63)) & 1ull);
            ull bal = __ballot(myhit);
            if (bal == 0ull) {                // keep o_cur
                if (lane == 0) keepS[fg*NPROP + o_cur] = 1;
                mask |= row_cur;
            }
            row_cur = row_next;
            o_cur = on;
        }
    }
    __syncthreads();
    // stage candidates to registers, then reuse keysL as compacted key buffer
    ull myKey[4]; int myKeep[4];
#pragma unroll
    for (int i = 0; i < 4; ++i) {
        int e = t + i*1024;
        myKey[i] = keysL[e];
        myKeep[i] = keepS[e];
    }
    __syncthreads();
    int myPos[4];
#pragma unroll
    for (int i = 0; i < 4; ++i)
        myPos[i] = myKeep[i] ? atomicAdd(&kcntS, 1) : -1;   // order-independent rank
    __syncthreads();
    int K = kcntS;
    int KP = (K + 15) & ~15;
#pragma unroll
    for (int i = 0; i < 4; ++i)
        if (myPos[i] >= 0) keysL[myPos[i]] = myKey[i];
    for (int k = K + t; k < KP; k += 1024) keysL[k] = 0ull;
    __syncthreads();
    // rank among kept; write top-100
    const float* boxes = ws + OFF_BOXES;
    for (int e = t; e < K; e += 1024) {
        ull my = keysL[e];
        int r = 0;
        for (int k = 0; k < KP; k += 16) {
            int acc = 0;
#pragma unroll
            for (int q = 0; q < 16; ++q)
                acc += (keysL[k+q] > my) ? 1 : 0;
            r += acc;
        }
        if (r < DET) {
            unsigned f = 0xFFFFFFFFu - (unsigned)(my & 0xFFFFFFFFu);   // flat-in-image
            float s = __uint_as_float((unsigned)(my >> 32));
            int src = b*FLAT_PER_IMG + (int)f;
            float* row = out + (b*DET + r)*6;
#pragma unroll
            for (int q = 0; q < 5; ++q) row[q] = boxes[src*5+q];
            row[5] = s;
            out[NB*DET*6 + b*DET + r] = (float)(f / NPROP + 1);
        }
    }
}

extern "C" void kernel_launch(void* const* d_in, const int* in_sizes, int n_in,
                              void* d_out, int out_size, void* d_ws, size_t ws_size,
                              hipStream_t stream) {
    const float* logits = (const float*)d_in[0];
    const float* boxreg = (const float*)d_in[1];
    const float* rrects = (const float*)d_in[2];
    float* out = (float*)d_out;
    float* ws  = (float*)d_ws;
    (void)in_sizes; (void)n_in; (void)out_size; (void)ws_size;

    pairheavy_kernel<<<BC_TOTAL * NSLICE, 768, 0, stream>>>(logits, boxreg, rrects, ws, out);
    finish_kernel<<<NB, 1024, 0, stream>>>(ws, out);
}

// Round 17
// 122.327 us; speedup vs baseline: 1.8848x; 1.8848x over previous
//
#include <hip/hip_runtime.h>
#include <cmath>

#define NPROP 384
#define NB 2
#define NCLS 11
#define NFG 10
#define BC_TOTAL (NB*NFG)          // 20
#define FLAT_PER_IMG (NFG*NPROP)   // 3840
#define DET 100
#define PAIR_LDS_CAP 4096
#define NSLICE 8
#define SLICE_CAP 9600             // worst-case suppress pairs per slice

// ws layout (in 4-byte words)
#define OFF_BOXES 0                // [BC][N][5]  38400
#define OFF_SCORE 38400            // [BC][N]     7680
#define OFF_KIDX  46080            // [BC][N] u32 kept flat-in-image idx (per-bc slices)
#define OFF_KSC   53760            // [BC][N] kept scores
#define OFF_KCNT  61440            // [BC] u32 kept counts
#define OFF_SCNT  61472            // [BC][8] u32 suppress-pair counts
#define OFF_SPAIR 61632            // [BC][8][SLICE_CAP] u32 suppress pairs

typedef unsigned long long ull;

__device__ __forceinline__ void mk_corners(float px, float py, float pw, float ph, float pa,
                                           float cxo[4], float cyo[4]) {
    float t = pa * 0.017453292519943295f;
    float ct = cosf(t), st = sinf(t);
    float hx = pw*0.5f, hy = ph*0.5f;
    float lx[4] = {-hx, hx, hx, -hx};
    float ly[4] = {-hy, -hy, hy, hy};
#pragma unroll
    for (int k = 0; k < 4; ++k) {
        cxo[k] = px + lx[k]*ct - ly[k]*st;
        cyo[k] = py + lx[k]*st + ly[k]*ct;
    }
}

// Register-only quirk-faithful intersection area (park-at-centroid + sort-all-24
// + shoelace). Bitonic-32 network keeps everything in VGPRs.
__device__ float inter_area_net(const float ax[4], const float ay[4],
                                const float bx[4], const float by[4]) {
    float d1x[4], d1y[4], d2x[4], d2y[4];
#pragma unroll
    for (int k = 0; k < 4; ++k) {
        int k1 = (k + 1) & 3;
        d1x[k] = ax[k1] - ax[k]; d1y[k] = ay[k1] - ay[k];
        d2x[k] = bx[k1] - bx[k]; d2y[k] = by[k1] - by[k];
    }
    float ex[32], ey[32];
    bool msk[24];
#pragma unroll
    for (int i = 0; i < 4; ++i) {
#pragma unroll
        for (int j = 0; j < 4; ++j) {
            float den = d1x[i]*d2y[j] - d1y[i]*d2x[j];
            float dfx = bx[j]-ax[i], dfy = by[j]-ay[i];
            float dens = (fabsf(den) < 1e-8f) ? 1.0f : den;
            float t = (dfx*d2y[j] - dfy*d2x[j]) / dens;
            float u = (dfx*d1y[i] - dfy*d1x[i]) / dens;
            bool ok = (fabsf(den) >= 1e-8f) && t >= 0.0f && t <= 1.0f
                                            && u >= 0.0f && u <= 1.0f;
            ex[i*4+j] = ax[i] + t*d1x[i];
            ey[i*4+j] = ay[i] + t*d1y[i];
            msk[i*4+j] = ok;
        }
    }
#pragma unroll
    for (int i = 0; i < 4; ++i) {   // corners of A inside B
        bool allp = true, alln = true;
#pragma unroll
        for (int j = 0; j < 4; ++j) {
            float cr = d2x[j]*(ay[i]-by[j]) - d2y[j]*(ax[i]-bx[j]);
            allp = allp && (cr >= -1e-6f);
            alln = alln && (cr <= 1e-6f);
        }
        ex[16+i] = ax[i]; ey[16+i] = ay[i]; msk[16+i] = allp || alln;
    }
#pragma unroll
    for (int i = 0; i < 4; ++i) {   // corners of B inside A
        bool allp = true, alln = true;
#pragma unroll
        for (int j = 0; j < 4; ++j) {
            float cr = d1x[j]*(by[i]-ay[j]) - d1y[j]*(bx[i]-ax[j]);
            allp = allp && (cr >= -1e-6f);
            alln = alln && (cr <= 1e-6f);
        }
        ex[20+i] = bx[i]; ey[20+i] = by[i]; msk[20+i] = allp || alln;
    }
    int nv = 0; float sx = 0.f, sy = 0.f;
#pragma unroll
    for (int k = 0; k < 24; ++k)
        if (msk[k]) { nv++; sx += ex[k]; sy += ey[k]; }
    float fm = (float)(nv > 1 ? nv : 1);
    float cx = sx / fm, cy = sy / fm;
    unsigned key[32];
#pragma unroll
    for (int k = 0; k < 24; ++k) {
        float qx = msk[k] ? ex[k] : cx;
        float qy = msk[k] ? ey[k] : cy;
        ex[k] = qx; ey[k] = qy;
        float dx = qx - cx, dy = qy - cy;        // parked: dx=dy=+0
        float den = fabsf(dx) + fabsf(dy);
        float r = (den > 0.0f) ? dy / den : 0.0f;
        float p = (dx >= 0.0f) ? r : ((dy >= 0.0f) ? 2.0f - r : -2.0f - r);
        p = p + 0.0f;                             // canonicalize -0 -> +0
        unsigned u = __float_as_uint(p);
        u = (u & 0x80000000u) ? ~u : (u | 0x80000000u);
        key[k] = (u & 0xFFFFFFE0u) | (unsigned)k;
    }
#pragma unroll
    for (int k = 24; k < 32; ++k) { key[k] = 0xFFFFFFFFu; ex[k] = 0.f; ey[k] = 0.f; }
#pragma unroll
    for (int k = 2; k <= 32; k <<= 1) {
#pragma unroll
        for (int j = k >> 1; j > 0; j >>= 1) {
#pragma unroll
            for (int i = 0; i < 32; ++i) {
                int l = i ^ j;
                if (l > i) {
                    bool up = ((i & k) == 0);
                    unsigned ka = key[i], kb = key[l];
                    bool sw = up ? (ka > kb) : (ka < kb);
                    float xa = ex[i], xb = ex[l];
                    float ya = ey[i], yb = ey[l];
                    key[i] = sw ? kb : ka; key[l] = sw ? ka : kb;
                    ex[i]  = sw ? xb : xa; ex[l]  = sw ? xa : xb;
                    ey[i]  = sw ? yb : ya; ey[l]  = sw ? ya : yb;
                }
            }
        }
    }
    float s = 0.f;
#pragma unroll
    for (int k = 0; k < 24; ++k) {
        int n = (k + 1 == 24) ? 0 : (k + 1);
        s += ex[k]*ey[n] - ey[k]*ex[n];
    }
    float area = 0.5f * fabsf(s);
    return (nv >= 3) ? area : 0.0f;
}

// K1: 160 blocks (20 bc x 8 slices) x 768 threads. decode (per-block, LDS) ->
// ballot valid-compact -> enumerate a = slice+8*wv+96*j -> AABB cull -> LDS
// pair list -> heavy eval -> append verified suppress pairs to global slice.
__global__ __launch_bounds__(768)
void pairheavy_kernel(const float* __restrict__ logits,
                      const float* __restrict__ boxreg,
                      const float* __restrict__ rrects,
                      float* __restrict__ ws,
                      float* __restrict__ out) {
    __shared__ float pxL[NPROP], pyL[NPROP], pwL[NPROP], phL[NPROP], paL[NPROP];
    __shared__ float areaL[NPROP], scoreL[NPROP];
    __shared__ float axhL[NPROP], ayhL[NPROP];
    __shared__ int   origL[NPROP];
    __shared__ unsigned pairL[PAIR_LDS_CAP];   // 16 KB
    __shared__ int   wbase[16];
    __shared__ int   totS, pcntS, scntS;

    int blk = blockIdx.x, t = threadIdx.x;
    int bc = blk >> 3, slice = blk & 7;
    int b = bc / NFG, cls = (bc % NFG) + 1;
    int wv = t >> 6, lane = t & 63;

    if (slice == 0) {                      // zero d_out once per bc-group
        int g = bc*768 + t;
        if (g < NB*DET*6 + NB*DET) out[g] = 0.0f;
    }
    if (t == 0) { pcntS = 0; scntS = 0; }

    // ---- decode (threads 0..383; global writes gated to slice 0) ----
    float prob = 0.0f;
    if (t < NPROP) {
        int m = b*NPROP + t;
        float lg[NCLS];
        float mx = -INFINITY;
#pragma unroll
        for (int c = 0; c < NCLS; ++c) { lg[c] = logits[m*NCLS+c]; mx = fmaxf(mx, lg[c]); }
        float sum = 0.f;
#pragma unroll
        for (int c = 0; c < NCLS; ++c) sum += expf(lg[c]-mx);
        prob = expf(lg[cls]-mx) / sum;
        float axc = rrects[m*5+0], ayc = rrects[m*5+1];
        float aw  = rrects[m*5+2], ah  = rrects[m*5+3], aa = rrects[m*5+4];
        const float* rel = boxreg + m*(NCLS*5) + cls*5;
        float dx = rel[0] / 10.0f;
        float dy = rel[1] / 10.0f;
        float dw = fminf(rel[2] / 5.0f, 4.1351665567423205f);
        float dh = fminf(rel[3] / 5.0f, 4.1351665567423205f);
        float da = rel[4];
        float px = dx*aw + axc;
        float py = dy*ah + ayc;
        float pw = expf(dw)*aw;
        float ph = expf(dh)*ah;
        float pa = da*57.29577951308232f + aa;
        float xm = pa + 180.0f;
        float r = fmodf(xm, 360.0f);
        if (r < 0.0f) r += 360.0f;
        pa = r - 180.0f;
        pxL[t]=px; pyL[t]=py; pwL[t]=pw; phL[t]=ph; paL[t]=pa;
        areaL[t]=pw*ph; scoreL[t]=prob;
        float th = pa * 0.017453292519943295f;
        float ct = fabsf(cosf(th)), st = fabsf(sinf(th));
        axhL[t] = 0.5f*(pw*ct + ph*st);
        ayhL[t] = 0.5f*(pw*st + ph*ct);
        if (slice == 0) {
            float* boxes = ws + OFF_BOXES;
            int o = bc*NPROP + t;
            boxes[o*5+0]=px; boxes[o*5+1]=py; boxes[o*5+2]=pw; boxes[o*5+3]=ph; boxes[o*5+4]=pa;
            ws[OFF_SCORE + o] = prob;
        }
    }
    // ---- ballot-prefix valid compaction ----
    bool vi = (t < NPROP) && (prob > 0.05f);
    ull vb = __ballot(vi);
    if (lane == 0) wbase[wv] = __popcll(vb);
    __syncthreads();
    if (t == 0) {
        int s = 0;
#pragma unroll
        for (int w = 0; w < 6; ++w) { int c = wbase[w]; wbase[w] = s; s += c; }
        totS = s;
    }
    __syncthreads();
    if (vi) origL[wbase[wv] + (int)__popcll(vb & ((1ull << lane) - 1ull))] = t;
    __syncthreads();
    int cnt = totS;

    unsigned int* spair = (unsigned int*)(ws + OFF_SPAIR) + (bc*NSLICE + slice)*SLICE_CAP;

    // ---- pair enumeration: a = slice + 8*wv + 96*j; AABB-upper-bound cull ----
    for (int a = slice + 8*wv; a < cnt; a += 96) {
        int ia = origL[a];
        float cxa = pxL[ia], cya = pyL[ia], Aa = areaL[ia], sa = scoreL[ia];
        float axa = axhL[ia], aya = ayhL[ia];
        for (int b0 = a + 1; b0 < cnt; b0 += 64) {
            int bb = b0 + lane;
            bool go = false; int ib = 0;
            if (bb < cnt) {
                ib = origL[bb];
                float ox = (axa + axhL[ib]) - fabsf(cxa - pxL[ib]);
                float oy = (aya + ayhL[ib]) - fabsf(cya - pyL[ib]);
                go = (ox > 0.0f) && (oy > 0.0f);
                if (go) {
                    float Ab = areaL[ib];
                    float ub = fminf(ox*oy, fminf(Aa, Ab));
                    go = (3.0f*ub > Aa + Ab);        // else iou <= 0.5 provably
                }
            }
            ull m = __ballot(go);
            int base = 0;
            if (lane == 0 && m) base = atomicAdd(&pcntS, __popcll(m));
            base = __shfl(base, 0);
            if (go) {
                float sb = scoreL[ib];
                bool afirst = (sa > sb) || (sa == sb && ia < ib);
                int hi = afirst ? ia : ib;
                int lo = afirst ? ib : ia;
                int pos = base + (int)__popcll(m & ((1ull << lane) - 1ull));
                if (pos < PAIR_LDS_CAP) {
                    pairL[pos] = ((unsigned)hi << 16) | (unsigned)lo;
                } else {                             // overflow: eval inline
                    float axp[4], ayp[4], bxp[4], byp[4];
                    mk_corners(pxL[hi], pyL[hi], pwL[hi], phL[hi], paL[hi], axp, ayp);
                    mk_corners(pxL[lo], pyL[lo], pwL[lo], phL[lo], paL[lo], bxp, byp);
                    float inter = inter_area_net(axp, ayp, bxp, byp);
                    float iou = inter / (areaL[hi] + areaL[lo] - inter + 1e-8f);
                    if (iou > 0.5f) {
                        int sp = atomicAdd(&scntS, 1);
                        if (sp < SLICE_CAP) spair[sp] = ((unsigned)hi << 10) | (unsigned)lo;
                    }
                }
            }
        }
    }
    __syncthreads();

    // ---- heavy eval over LDS pair list; survivors -> global suppress slice ----
    {
        int np = pcntS; if (np > PAIR_LDS_CAP) np = PAIR_LDS_CAP;
        for (int p = t; p < np; p += 768) {
            unsigned pk = pairL[p];
            int hi = (int)(pk >> 16), lo = (int)(pk & 0xFFFFu);
            float axp[4], ayp[4], bxp[4], byp[4];
            mk_corners(pxL[hi], pyL[hi], pwL[hi], phL[hi], paL[hi], axp, ayp);
            mk_corners(pxL[lo], pyL[lo], pwL[lo], phL[lo], paL[lo], bxp, byp);
            float inter = inter_area_net(axp, ayp, bxp, byp);
            float iou = inter / (areaL[hi] + areaL[lo] - inter + 1e-8f);
            if (iou > 0.5f) {
                int sp = atomicAdd(&scntS, 1);
                if (sp < SLICE_CAP) spair[sp] = ((unsigned)hi << 10) | (unsigned)lo;
            }
        }
    }
    __syncthreads();
    if (t == 0) {
        int n = scntS; if (n > SLICE_CAP) n = SLICE_CAP;
        ((unsigned int*)(ws + OFF_SCNT))[bc*NSLICE + slice] = (unsigned)n;
    }
}

// K2: 20 blocks x 384. keys + rank-sort, scatter suppress pairs into LDS sup
// matrix, register-walk NMS, ballot kept-append.
__global__ __launch_bounds__(384)
void nms_kernel(float* __restrict__ ws) {
    __shared__ ull keyL[NPROP];
    __shared__ ull supL[NPROP*6];          // 18.4 KB
    __shared__ int orderL[NPROP];
    __shared__ unsigned char keepS[NPROP];
    __shared__ int wbase[8];
    int bc = blockIdx.x, t = threadIdx.x;
    int wv = t >> 6, lane = t & 63;
    float sc = ws[OFF_SCORE + bc*NPROP + t];
    bool vi = sc > 0.05f;
    ull myk = vi ? (((ull)__float_as_uint(sc) << 32) | (ull)(0xFFFFFFFFu - (unsigned)t))
                 : (ull)(0xFFFFFFFFu - (unsigned)t);
    keyL[t] = myk;
    keepS[t] = 0;
    for (int k = t; k < NPROP*6; k += NPROP) supL[k] = 0ull;
    ull vb = __ballot(vi);
    if (lane == 0) wbase[wv] = __popcll(vb);
    __syncthreads();
    int NV = wbase[0] + wbase[1] + wbase[2] + wbase[3] + wbase[4] + wbase[5];
    {
        int r = 0;
        for (int k = 0; k < NPROP; k += 8) {
            int acc = 0;
#pragma unroll
            for (int q = 0; q < 8; ++q) acc += (keyL[k+q] > myk) ? 1 : 0;
            r += acc;
        }
        orderL[r] = t;
    }
    // scatter suppress pairs into LDS sup matrix
    const unsigned int* scnt = (const unsigned int*)(ws + OFF_SCNT);
#pragma unroll
    for (int s = 0; s < NSLICE; ++s) {
        int n = (int)scnt[bc*NSLICE + s];
        const unsigned int* spair = (const unsigned int*)(ws + OFF_SPAIR)
                                    + (bc*NSLICE + s)*SLICE_CAP;
        for (int k = t; k < n; k += NPROP) {
            unsigned pk = spair[k];
            int hi = (int)(pk >> 10), lo = (int)(pk & 0x3FFu);
            atomicOr((unsigned int*)supL + hi*12 + (lo >> 5), 1u << (lo & 31));
        }
    }
    __syncthreads();
    // register-resident wave-parallel NMS walk (wave 0)
    if (t < 64) {
        int ord0 = orderL[lane],      ord1 = orderL[64+lane];
        int ord2 = orderL[128+lane],  ord3 = orderL[192+lane];
        int ord4 = orderL[256+lane],  ord5 = orderL[320+lane];
        ull mask = 0ull;                      // lanes 0..5: 384-bit suppressed set
        int o_cur = __shfl(ord0, 0);
        ull row_cur = (lane < 6) ? supL[o_cur*6 + lane] : 0ull;
        for (int p = 0; p < NV; ++p) {
            int pn = (p + 1 < NPROP) ? (p + 1) : 0;
            int seg = pn >> 6, sl = pn & 63;
            int on = __shfl(ord0, sl);
            on = (seg == 1) ? __shfl(ord1, sl) : on;
            on = (seg == 2) ? __shfl(ord2, sl) : on;
            on = (seg == 3) ? __shfl(ord3, sl) : on;
            on = (seg == 4) ? __shfl(ord4, sl) : on;
            on = (seg == 5) ? __shfl(ord5, sl) : on;
            ull row_next = (lane < 6) ? supL[on*6 + lane] : 0ull;  // prefetch
            bool myhit = (lane == (o_cur >> 6)) && ((mask >> (o_cur & 63)) & 1ull);
            ull bal = __ballot(myhit);
            if (bal == 0ull) {                // keep o_cur
                if (lane == 0) keepS[o_cur] = 1;
                mask |= row_cur;
            }
            row_cur = row_next;
            o_cur = on;
        }
    }
    __syncthreads();
    // kept append into this bc's slice (ballot prefix, no atomics)
    bool kp = keepS[t] != 0;
    ull bal = __ballot(kp);
    if (lane == 0) wbase[wv] = __popcll(bal);
    __syncthreads();
    if (t == 0) {
        int s = 0;
#pragma unroll
        for (int w = 0; w < 6; ++w) { int c = wbase[w]; wbase[w] = s; s += c; }
        ((unsigned int*)(ws + OFF_KCNT))[bc] = (unsigned)s;
    }
    __syncthreads();
    if (kp) {
        int pos = wbase[wv] + (int)__popcll(bal & ((1ull << lane) - 1ull));
        ((unsigned int*)(ws + OFF_KIDX))[bc*NPROP + pos] = (unsigned)((bc % NFG)*NPROP + t);
        (ws + OFF_KSC)[bc*NPROP + pos] = sc;
    }
}

// K3: 16 blocks per image; concat kept slices as u64 keys in LDS; rank count.
__global__ __launch_bounds__(256)
void topk_kernel(const float* __restrict__ ws, float* __restrict__ out) {
    __shared__ ull keyL[FLAT_PER_IMG];
    int b = blockIdx.x >> 4;
    int slice = blockIdx.x & 15;
    int t = threadIdx.x;
    const unsigned int* kidx2 = (const unsigned int*)(ws + OFF_KIDX);
    const float* ksc2 = ws + OFF_KSC;
    const unsigned int* kcnt2 = (const unsigned int*)(ws + OFF_KCNT);
    const float* boxes = ws + OFF_BOXES;
    int offs[NFG], cnts[NFG];
    int K = 0;
#pragma unroll
    for (int fg = 0; fg < NFG; ++fg) {
        cnts[fg] = (int)kcnt2[b*NFG + fg];
        offs[fg] = K;
        K += cnts[fg];
    }
#pragma unroll
    for (int fg = 0; fg < NFG; ++fg) {
        int bc = b*NFG + fg;
        for (int k = t; k < cnts[fg]; k += 256) {
            unsigned sb = __float_as_uint(ksc2[bc*NPROP + k]);
            unsigned f  = kidx2[bc*NPROP + k];
            keyL[offs[fg] + k] = ((ull)sb << 32) | (ull)(0xFFFFFFFFu - f);
        }
    }
    int KP = (K + 15) & ~15;
    for (int k = K + t; k < KP; k += 256) keyL[k] = 0ull;
    __syncthreads();
    int e = slice*256 + t;
    if (e >= K) return;
    ull my = keyL[e];
    int r = 0;
    for (int k = 0; k < KP; k += 16) {
        int acc = 0;
#pragma unroll
        for (int q = 0; q < 16; ++q)
            acc += (keyL[k+q] > my) ? 1 : 0;
        r += acc;
    }
    if (r < DET) {
        unsigned f = 0xFFFFFFFFu - (unsigned)(my & 0xFFFFFFFFu);
        float s = __uint_as_float((unsigned)(my >> 32));
        int src = b*FLAT_PER_IMG + (int)f;
        float* row = out + (b*DET + r)*6;
#pragma unroll
        for (int q = 0; q < 5; ++q) row[q] = boxes[src*5+q];
        row[5] = s;
        out[NB*DET*6 + b*DET + r] = (float)(f / NPROP + 1);
    }
}

extern "C" void kernel_launch(void* const* d_in, const int* in_sizes, int n_in,
                              void* d_out, int out_size, void* d_ws, size_t ws_size,
                              hipStream_t stream) {
    const float* logits = (const float*)d_in[0];
    const float* boxreg = (const float*)d_in[1];
    const float* rrects = (const float*)d_in[2];
    float* out = (float*)d_out;
    float* ws  = (float*)d_ws;
    (void)in_sizes; (void)n_in; (void)out_size; (void)ws_size;

    pairheavy_kernel<<<BC_TOTAL * NSLICE, 768, 0, stream>>>(logits, boxreg, rrects, ws, out);
    nms_kernel<<<BC_TOTAL, NPROP, 0, stream>>>(ws);
    topk_kernel<<<NB * 16, 256, 0, stream>>>(ws, out);
}